// Round 8
// baseline (191.109 us; speedup 1.0000x reference)
//
#include <hip/hip_runtime.h>
#include <math.h>

typedef unsigned short u16;
typedef unsigned int u32;
typedef __attribute__((ext_vector_type(8))) short bf16x8;   // 8 bf16 = 4 VGPR (MFMA A/B frag)
typedef __attribute__((ext_vector_type(4))) float f32x4;    // MFMA C/D frag
typedef __attribute__((ext_vector_type(2))) float f32x2;    // packed fp32 pair (v_pk_fma_f32)

__device__ __forceinline__ u16 f32_to_bf16(float f) {
    u32 u = __float_as_uint(f);
    u32 r = u + 0x7FFFu + ((u >> 16) & 1u);   // round-to-nearest-even
    return (u16)(r >> 16);
}
__device__ __forceinline__ u32 pack2(u16 a, u16 b) { return (u32)a | ((u32)b << 16); }

// RNE-rounded bf16 pair pack via v_perm
__device__ __forceinline__ u32 rne_bits(float f) {
    u32 u = __float_as_uint(f);
    return u + 0x7FFFu + ((u >> 16) & 1u);
}
__device__ __forceinline__ u32 pack_rne(float a, float b) {
    return __builtin_amdgcn_perm(rne_bits(b), rne_bits(a), 0x07060302u);
}

// fast tanh via hardware exp
__device__ __forceinline__ float fast_tanh(float x) {
    float e = __expf(2.f * x);
    return 1.f - 2.f / (e + 1.f);
}

// ---------------- quantum gate helpers (prep only; precise libm) ----------------
template<int STRIDE>
__device__ __forceinline__ void ry_gate(float st[16], float theta) {
    float s, c;
    sincosf(theta * 0.5f, &s, &c);
#pragma unroll
    for (int i = 0; i < 16; ++i) {
        if (i & STRIDE) continue;
        float s0 = st[i], s1 = st[i | STRIDE];
        st[i]          = c * s0 - s * s1;
        st[i | STRIDE] = fmaf(s, s0, c * s1);
    }
}
template<int CS, int TS>
__device__ __forceinline__ void cnot_gate(float st[16]) {
#pragma unroll
    for (int i = 0; i < 16; ++i) {
        if ((i & CS) && !(i & TS)) {
            float tmp = st[i]; st[i] = st[i | TS]; st[i | TS] = tmp;
        }
    }
}

// ---------------- Prep: fcw transpose->bf16, w2->bf16 frag layout, circuit matrix M ----------
// whi: [f][k = op*64+oc] (k_ref = oc*16+op). w2b: [(t*64+oc)*32+ic] bf16.
__global__ __launch_bounds__(256) void prep_kernel(
    const float* __restrict__ fcw, const float* __restrict__ w2,
    const float* __restrict__ qp,
    u16* __restrict__ whi, u16* __restrict__ w2b, float* __restrict__ Mg)
{
    const int f  = blockIdx.x;         // 0..63
    const int k0 = threadIdx.x * 4;    // 0..1020
    u16 hv[4];
#pragma unroll
    for (int i = 0; i < 4; ++i) {
        int k  = k0 + i;
        int op = k >> 6, oc = k & 63;
        hv[i] = f32_to_bf16(fcw[(size_t)(oc * 16 + op) * 64 + f]);
    }
    *(uint2*)(whi + (size_t)f * 1024 + k0) = make_uint2(pack2(hv[0], hv[1]), pack2(hv[2], hv[3]));

    if (threadIdx.x < 96) {
        const int j  = threadIdx.x;
        const int ic = j / 3, t = j - ic * 3;
        w2b[(t * 64 + f) * 32 + ic] = f32_to_bf16(w2[f * 96 + j]);
    }

    if (blockIdx.x == 0 && threadIdx.x < 16) {
        const int j = threadIdx.x;
        float st[16];
#pragma unroll
        for (int i = 0; i < 16; ++i) st[i] = (i == j) ? 1.f : 0.f;
        for (int k = 0; k < 6; ++k) {
            cnot_gate<8, 4>(st);   // CNOT(0,1)
            cnot_gate<2, 1>(st);   // CNOT(2,3)
            cnot_gate<4, 2>(st);   // CNOT(1,2)
            ry_gate<8>(st, qp[k * 4 + 0]);
            ry_gate<4>(st, qp[k * 4 + 1]);
            ry_gate<2>(st, qp[k * 4 + 2]);
            ry_gate<1>(st, qp[k * 4 + 3]);
        }
#pragma unroll
        for (int i = 0; i < 16; ++i) Mg[i * 16 + j] = st[i];
    }
}

// ---------------- Fused: conv1 -> conv2(MFMA) -> fc(MFMA) -> quantum epilogue ----------------
// R23 = R21 tile (16 samples) with 1024 THREADS / 16 WAVES, per-wave work halved, 2 blk/CU.
// R22 post-mortem: CP-amortization via bigger tile REFUTED (62 -> 75.7us at 32 samples /
// 1 blk/CU). Ranking: R20/R21 (16smp, 8wv, 3blk) = 62 best. Model update: nothing saturated
// (VALU 30, MFMA 11, HBM 1%) and Occupancy 35% (~11 of 24 resident waves active) ->
// binding resource = waves-in-flight x independent work. R23 raises both knobs:
//  - conv1: 64 thr/sample, thread = (position pp, icp-half), 8 icp each (VALU + s-loads /2)
//  - conv2: wave wv -> sample wv (2 q-halves). NO-BARRIER INVARIANT EXACT: conv1 threads
//    tid>>6==wv wrote sample wv - same wave, in-order LDS.
//  - fc: 16 waves = 4 feat-groups (g=wv&3) x 4 kc-quarters (hq=wv>>2), chain 16->8;
//    quarters 1-3 store part3, quarter 0 combines (+fcb, relu) after B1. 3 barriers total.
//  - epilogue: wave 0, 64 lanes (R19-verified geometry: s=lane>>2, L=lane&3).
//  - hfl in a DEDICATED buffer (no c1h aliasing).
// LDS 64.6KB -> 2 blocks/CU x 16 waves = 32 waves/CU (100% slot fill vs 24).
// (1024,4) = VGPR cap 128, the verified no-spill bucket (R16 lesson: never request odd
// wave counts). Spill canary: WRITE_SIZE ~0.13 MB, VGPR ~52.
// Per-sample block in c1h (1384 u16): c1T rows p[0,34) stride 40 (halo rows 0,33 zero);
// hT aliased (same-wave read-before-write) op-chunk stride 72.
__global__ __launch_bounds__(1024, 4) void fused_kernel(
    const float* __restrict__ x,
    const float* __restrict__ w1, const float* __restrict__ b1,
    const u16* __restrict__ w2b, const float* __restrict__ b2,
    const u16* __restrict__ whi,
    const float* __restrict__ fcb,
    const float* __restrict__ prew, const float* __restrict__ preb,
    const float* __restrict__ postw, const float* __restrict__ postb,
    const float* __restrict__ Mg,
    float* __restrict__ out)
{
    __shared__ __align__(16) u16 c1h[16 * 1384];     // 44.3 KB
    __shared__ __align__(16) float part3[3 * 1280];  // 15.4 KB fc quarter partials, stride 20
    __shared__ __align__(16) float hflb[16 * 68];    // 4.3 KB fc output [sample][feat], stride 68
    __shared__ float prews[256];                     // 1 KB
    __shared__ float Ms[16][17];                     // 1.1 KB

    const int tid  = threadIdx.x;
    const int bs   = blockIdx.x * 16;
    const int wv   = tid >> 6, lane = tid & 63;
    const int lr   = lane & 15, lq = lane >> 4;

    // ---- stage small tables (consumed after barrier B2 -> visible) ----
    if (tid < 256) {
        prews[tid] = prew[tid];
        Ms[tid >> 4][tid & 15] = Mg[tid];
    }

    // ---- x loads FIRST (vmcnt in-order: conv1's wait won't drain later af loads) ----
    const int s1   = tid >> 6;       // 0..15 sample (== wv)
    const int th   = tid & 63;
    const int pp   = th & 31;        // position pair, p = pp+1
    const int half = th >> 5;        // icp half: channels [half*16, half*16+16)
    const float* xb = x + (size_t)(bs + s1) * 64;
    const int j = 2 * pp;
    float xm1 = (j == 0)  ? 0.f : xb[j - 1];
    float x0  = xb[j];
    float x1  = xb[j + 1];
    float xp2 = (j == 62) ? 0.f : xb[j + 2];

    // ---- conv2 weight frags issued now; latency hides under conv1 arithmetic ----
    bf16x8 af[3][4];
#pragma unroll
    for (int t = 0; t < 3; ++t)
#pragma unroll
        for (int mt = 0; mt < 4; ++mt)
            af[t][mt] = *(const bf16x8*)(w2b + (size_t)(t * 64 + mt * 16 + lr) * 32 + lq * 8);
    f32x4 bias2[4];
#pragma unroll
    for (int mt = 0; mt < 4; ++mt)
        bias2[mt] = *(const f32x4*)(b2 + mt * 16 + lq * 4);

    // ---- conv1 + relu + pool2 -> c1T; each thread: 8 icp (16 channels) of one position ----
    {
        u16* sbase = c1h + s1 * 1384;
        if (half == 0 && (pp == 0 || pp == 31)) {   // halo rows 0 and 33
            uint4 z = make_uint4(0, 0, 0, 0);
            uint4* zr = (uint4*)(sbase + (pp == 0 ? 0 : 33) * 40);
            zr[0] = z; zr[1] = z; zr[2] = z; zr[3] = z;
        }
        const f32x2 A1 = {xm1, x0};
        const f32x2 A2 = {x0,  x1};
        const f32x2 A3 = {x1,  xp2};
        u32 row[8];
#pragma unroll
        for (int icp = 0; icp < 8; ++icp) {
            float v[2];
#pragma unroll
            for (int h2 = 0; h2 < 2; ++h2) {
                int ic = (half * 8 + icp) * 2 + h2;
                // wave-uniform indices -> scalar loads on the s-pipe
                float wa = w1[ic * 3], wb = w1[ic * 3 + 1], wc = w1[ic * 3 + 2], bb = b1[ic];
                f32x2 Y = {bb, bb};
                Y += wa * A1;
                Y += wb * A2;
                Y += wc * A3;
                v[h2] = fmaxf(fmaxf(Y.x, Y.y), 0.f);   // pool + relu (v_max3)
            }
            row[icp] = pack_rne(v[0], v[1]);
        }
        uint4* d = (uint4*)(sbase + (1 + pp) * 40 + half * 16);
        d[0] = make_uint4(row[0], row[1], row[2], row[3]);
        d[1] = make_uint4(row[4], row[5], row[6], row[7]);
    }
    // NO barrier: conv1 threads of wave wv wrote exactly sample wv (s1 = tid>>6 = wv);
    // conv2 wave wv reads only sample wv. Same-wave LDS ops are in-order -> RAW safe.

    // ---- conv2 via MFMA (bias as C-init) + pool -> hT aliased into c1h ----
#pragma unroll
    for (int nt = 0; nt < 2; ++nt) {              // wave wv -> sample wv; two q-halves
        const int s  = wv;
        const int qb = nt * 16;
        const u16* bp = c1h + s * 1384 + (qb + lr) * 40 + lq * 8;
        bf16x8 bf0 = *(const bf16x8*)(bp);        // tap t=0
        bf16x8 bf1 = *(const bf16x8*)(bp + 40);   // t=1 (+1 row)
        bf16x8 bf2 = *(const bf16x8*)(bp + 80);   // t=2 (+2 rows)
        const int op = (qb + lr) >> 1;
#pragma unroll
        for (int mt = 0; mt < 4; ++mt) {          // interleaved epilogue: acc live = 4
            f32x4 acc = __builtin_amdgcn_mfma_f32_16x16x32_bf16(af[0][mt], bf0, bias2[mt], 0, 0, 0);
            acc = __builtin_amdgcn_mfma_f32_16x16x32_bf16(af[1][mt], bf1, acc, 0, 0, 0);
            acc = __builtin_amdgcn_mfma_f32_16x16x32_bf16(af[2][mt], bf2, acc, 0, 0, 0);
            float p0 = fmaxf(fmaxf(acc[0], __shfl_xor(acc[0], 1)), 0.f);
            float p1 = fmaxf(fmaxf(acc[1], __shfl_xor(acc[1], 1)), 0.f);
            float p2 = fmaxf(fmaxf(acc[2], __shfl_xor(acc[2], 1)), 0.f);
            float p3 = fmaxf(fmaxf(acc[3], __shfl_xor(acc[3], 1)), 0.f);
            if (!(lane & 1)) {
                *(uint2*)(c1h + s * 1384 + op * 72 + mt * 16 + lq * 4) =
                    make_uint2(pack_rne(p0, p1), pack_rne(p2, p3));
            }
        }
    }
    __syncthreads();   // barrier A: fc reads hT across all samples/waves

    // ---- fc via MFMA on ALL 16 waves: g = wv&3 feature group (16 feats),
    //      hq = wv>>2 kc-quarter (8 kc, chain-8). Per wave: 8 x (A-read + B-load + MFMA). ----
    const int g  = wv & 3;
    const int hq = wv >> 2;
    const int n0 = g * 16;
    f32x4 acc0 = {0.f, 0.f, 0.f, 0.f};
    {
        const u16* ab0 = c1h + (size_t)lr * 1384 + lq * 8;
        const u16* bh0 = whi + (size_t)(n0 + lr) * 1024 + hq * 8 * 32 + lq * 8;
#pragma unroll
        for (int i = 0; i < 8; ++i) {
            const int kc = hq * 8 + i;
            const int aoff = (kc >> 1) * 72 + (kc & 1) * 32;
            bf16x8 a0 = *(const bf16x8*)(ab0 + aoff);
            bf16x8 f0 = *(const bf16x8*)(bh0 + i * 32);
            acc0 = __builtin_amdgcn_mfma_f32_16x16x32_bf16(a0, f0, acc0, 0, 0, 0);
        }
    }
    // quarters 1-3 store partials: D row = lq*4+r = sample, col = lr -> feature n0+lr
    if (hq) {
        *(f32x4*)(&part3[(hq - 1) * 1280 + (n0 + lr) * 20 + lq * 4]) = acc0;
    }
    __syncthreads();   // barrier B1: partials visible
    if (hq == 0) {
        const f32x4 p1_ = *(const f32x4*)(&part3[0 * 1280 + (n0 + lr) * 20 + lq * 4]);
        const f32x4 p2_ = *(const f32x4*)(&part3[1 * 1280 + (n0 + lr) * 20 + lq * 4]);
        const f32x4 p3_ = *(const f32x4*)(&part3[2 * 1280 + (n0 + lr) * 20 + lq * 4]);
        const float fb0 = fcb[n0 + lr];
#pragma unroll
        for (int r = 0; r < 4; ++r) {
            hflb[(lq * 4 + r) * 68 + n0 + lr] =
                fmaxf(acc0[r] + p1_[r] + p2_[r] + p3_[r] + fb0, 0.f);
        }
    }
    __syncthreads();   // barrier B2: epilogue reads hflb

    // ---- epilogue on WAVE 0 at full 64-lane utilization: s = lane>>2 (0..15), 4 lanes/sample ----
    if (wv == 0) {
        const int L = lane & 3;
        const int s = lane >> 2;
        const float* hfl = hflb + s * 68;

        float a0 = 0.f, a1 = 0.f, a2 = 0.f, a3 = 0.f;
#pragma unroll
        for (int i2 = 0; i2 < 4; ++i2) {
            float4 hv = *(const float4*)(hfl + L * 16 + i2 * 4);
#pragma unroll
            for (int c = 0; c < 4; ++c) {
                int ff = L * 16 + i2 * 4 + c;
                float4 pw = *(const float4*)&prews[ff * 4];
                float hx = (c == 0) ? hv.x : (c == 1) ? hv.y : (c == 2) ? hv.z : hv.w;
                a0 = fmaf(hx, pw.x, a0);
                a1 = fmaf(hx, pw.y, a1);
                a2 = fmaf(hx, pw.z, a2);
                a3 = fmaf(hx, pw.w, a3);
            }
        }
        // reduce across the 4 lanes of this sample (xor 1,2 stay within the lane quad)
        a0 += __shfl_xor(a0, 1); a0 += __shfl_xor(a0, 2);
        a1 += __shfl_xor(a1, 1); a1 += __shfl_xor(a1, 2);
        a2 += __shfl_xor(a2, 1); a2 += __shfl_xor(a2, 2);
        a3 += __shfl_xor(a3, 1); a3 += __shfl_xor(a3, 2);

        const float HP = 1.5707963267948966f;
        float qin[4] = { fast_tanh(a0 + preb[0]) * HP, fast_tanh(a1 + preb[1]) * HP,
                         fast_tanh(a2 + preb[2]) * HP, fast_tanh(a3 + preb[3]) * HP };

        float va[4], vb[4];
        const float RS = 0.70710678118654752f;
#pragma unroll
        for (int w = 0; w < 4; ++w) {
            float sw, cw;
            __sincosf(qin[w] * 0.5f, &sw, &cw);
            va[w] = (cw - sw) * RS;
            vb[w] = (sw + cw) * RS;
        }
        float sv[16];
#pragma unroll
        for (int jj = 0; jj < 16; ++jj) {
            float t = (jj & 8) ? vb[0] : va[0];
            t *= (jj & 4) ? vb[1] : va[1];
            t *= (jj & 2) ? vb[2] : va[2];
            t *= (jj & 1) ? vb[3] : va[3];
            sv[jj] = t;
        }
        float z0 = 0.f, z1 = 0.f, z2 = 0.f, z3 = 0.f;
#pragma unroll
        for (int rr = 0; rr < 4; ++rr) {
            const int r = L * 4 + rr;
            float m = 0.f;
#pragma unroll
            for (int jj = 0; jj < 16; ++jj) m = fmaf(Ms[r][jj], sv[jj], m);
            float p = m * m;
            z0 += (r & 8) ? -p : p;
            z1 += (r & 4) ? -p : p;
            z2 += (r & 2) ? -p : p;
            z3 += (r & 1) ? -p : p;
        }
        z0 += __shfl_xor(z0, 1); z0 += __shfl_xor(z0, 2);
        z1 += __shfl_xor(z1, 1); z1 += __shfl_xor(z1, 2);
        z2 += __shfl_xor(z2, 1); z2 += __shfl_xor(z2, 2);
        z3 += __shfl_xor(z3, 1); z3 += __shfl_xor(z3, 2);

        if (L == 0) {
            float t = postb[0] + z0 * postw[0] + z1 * postw[1] + z2 * postw[2] + z3 * postw[3];
            out[bs + s] = 1.f / (1.f + __expf(-t));
        }
    }
}

extern "C" void kernel_launch(void* const* d_in, const int* in_sizes, int n_in,
                              void* d_out, int out_size, void* d_ws, size_t ws_size,
                              hipStream_t stream) {
    const float* x     = (const float*)d_in[0];
    const float* w1    = (const float*)d_in[1];
    const float* b1    = (const float*)d_in[2];
    const float* w2    = (const float*)d_in[3];
    const float* b2    = (const float*)d_in[4];
    const float* fcw   = (const float*)d_in[5];
    const float* fcb   = (const float*)d_in[6];
    const float* prew  = (const float*)d_in[7];
    const float* preb  = (const float*)d_in[8];
    const float* qp    = (const float*)d_in[9];
    const float* postw = (const float*)d_in[10];
    const float* postb = (const float*)d_in[11];
    float* out = (float*)d_out;

    u16*   fwhi = (u16*)d_ws;                           // 64*1024 bf16 = 128 KiB
    float* Mg   = (float*)((char*)d_ws + 131072);       // 1 KiB
    u16*   w2b  = (u16*)((char*)d_ws + 132096);         // 12 KiB

    const int B = in_sizes[0] / 64;   // 32768

    prep_kernel<<<dim3(64), dim3(256), 0, stream>>>(fcw, w2, qp, fwhi, w2b, Mg);
    fused_kernel<<<dim3(B / 16), dim3(1024), 0, stream>>>(x, w1, b1, w2b, b2,
                                                          fwhi, fcb, prew, preb,
                                                          postw, postb, Mg, out);
}

// Round 9
// 135.652 us; speedup vs baseline: 1.4088x; 1.4088x over previous
//
#include <hip/hip_runtime.h>
#include <math.h>

typedef unsigned short u16;
typedef unsigned int u32;
typedef __attribute__((ext_vector_type(8))) short bf16x8;   // 8 bf16 = 4 VGPR (MFMA A/B frag)
typedef __attribute__((ext_vector_type(4))) float f32x4;    // MFMA C/D frag
typedef __attribute__((ext_vector_type(2))) float f32x2;    // packed fp32 pair (v_pk_fma_f32)

__device__ __forceinline__ u16 f32_to_bf16(float f) {
    u32 u = __float_as_uint(f);
    u32 r = u + 0x7FFFu + ((u >> 16) & 1u);   // round-to-nearest-even
    return (u16)(r >> 16);
}
__device__ __forceinline__ u32 pack2(u16 a, u16 b) { return (u32)a | ((u32)b << 16); }

// RNE-rounded bf16 pair pack via v_perm
__device__ __forceinline__ u32 rne_bits(float f) {
    u32 u = __float_as_uint(f);
    return u + 0x7FFFu + ((u >> 16) & 1u);
}
__device__ __forceinline__ u32 pack_rne(float a, float b) {
    return __builtin_amdgcn_perm(rne_bits(b), rne_bits(a), 0x07060302u);
}

// fast tanh via hardware exp
__device__ __forceinline__ float fast_tanh(float x) {
    float e = __expf(2.f * x);
    return 1.f - 2.f / (e + 1.f);
}

// ---------------- quantum gate helpers (prep only; precise libm) ----------------
template<int STRIDE>
__device__ __forceinline__ void ry_gate(float st[16], float theta) {
    float s, c;
    sincosf(theta * 0.5f, &s, &c);
#pragma unroll
    for (int i = 0; i < 16; ++i) {
        if (i & STRIDE) continue;
        float s0 = st[i], s1 = st[i | STRIDE];
        st[i]          = c * s0 - s * s1;
        st[i | STRIDE] = fmaf(s, s0, c * s1);
    }
}
template<int CS, int TS>
__device__ __forceinline__ void cnot_gate(float st[16]) {
#pragma unroll
    for (int i = 0; i < 16; ++i) {
        if ((i & CS) && !(i & TS)) {
            float tmp = st[i]; st[i] = st[i | TS]; st[i | TS] = tmp;
        }
    }
}

// ---------------- Prep: fcw transpose->bf16, w2->bf16 frag layout, circuit matrix M ----------
// whi: [f][k = op*64+oc] (k_ref = oc*16+op). w2b: [(t*64+oc)*32+ic] bf16.
__global__ __launch_bounds__(256) void prep_kernel(
    const float* __restrict__ fcw, const float* __restrict__ w2,
    const float* __restrict__ qp,
    u16* __restrict__ whi, u16* __restrict__ w2b, float* __restrict__ Mg)
{
    const int f  = blockIdx.x;         // 0..63
    const int k0 = threadIdx.x * 4;    // 0..1020
    u16 hv[4];
#pragma unroll
    for (int i = 0; i < 4; ++i) {
        int k  = k0 + i;
        int op = k >> 6, oc = k & 63;
        hv[i] = f32_to_bf16(fcw[(size_t)(oc * 16 + op) * 64 + f]);
    }
    *(uint2*)(whi + (size_t)f * 1024 + k0) = make_uint2(pack2(hv[0], hv[1]), pack2(hv[2], hv[3]));

    if (threadIdx.x < 96) {
        const int j  = threadIdx.x;
        const int ic = j / 3, t = j - ic * 3;
        w2b[(t * 64 + f) * 32 + ic] = f32_to_bf16(w2[f * 96 + j]);
    }

    if (blockIdx.x == 0 && threadIdx.x < 16) {
        const int j = threadIdx.x;
        float st[16];
#pragma unroll
        for (int i = 0; i < 16; ++i) st[i] = (i == j) ? 1.f : 0.f;
        for (int k = 0; k < 6; ++k) {
            cnot_gate<8, 4>(st);   // CNOT(0,1)
            cnot_gate<2, 1>(st);   // CNOT(2,3)
            cnot_gate<4, 2>(st);   // CNOT(1,2)
            ry_gate<8>(st, qp[k * 4 + 0]);
            ry_gate<4>(st, qp[k * 4 + 1]);
            ry_gate<2>(st, qp[k * 4 + 2]);
            ry_gate<1>(st, qp[k * 4 + 3]);
        }
#pragma unroll
        for (int i = 0; i < 16; ++i) Mg[i * 16 + j] = st[i];
    }
}

// ---------------- Fused: conv1 -> conv2(MFMA) -> fc(MFMA) -> quantum epilogue ----------------
// R24 = R21 (62us champion: 16 samples / 512 thr / 8 waves) + BARRIER MERGE + full fc unroll.
// R23 post-mortem (114us): conv1 icp-split made w1/b1 indices LANE-VARYING -> lost the
// wave-uniform scalar-load property (SGPR 112->48 is the tell), 64 lanes x 64 VMEM loads
// clogged the vmcnt queue. Invariant recorded: conv1 weight indices must be wave-uniform.
// Ranking: R21 62 < R17 68 < R15 70 < R22 75.7 < R23 114. Structural gambles lose; phase
// cuts win. R24 cuts the post-fc chain {store -> B1 -> combine+hflb -> B2} to
// {store both halves -> B}: ALL 8 fc waves store partials to part2[2][1280] (stride 20),
// combine phase and hflb deleted, wave-0 epilogue fuses h = relu(p0+p1+fcb) inline (fcb
// staged in LDS). Saves one barrier drain + one LDS roundtrip per round. LDS 51.7->55.6KB
// -> 2 blk/CU (known-cheap: R15 1blk ~= R17 3blk within 3%). With VGPR slack at 2 blk
// (cap 128), fc loop fully unrolled (16): all whi loads batch after barrier A -> one L2
// latency exposure. Spill canary: WRITE_SIZE ~0.13MB, VGPR < 128, no scratch.
// Carried invariants: no barrier before conv2 (conv1 wave wv writes exactly samples
// {2wv,2wv+1}, conv2 wave wv reads only those - same-wave in-order LDS); conv2 weight
// frags issued after x loads, before conv1 arithmetic (vmcnt in-order); epilogue wave 0
// at full 64-lane util (s=lane>>2, L=lane&3 - R19-verified). Per-sample block in c1h
// (1384 u16): c1T rows p[0,34) stride 40 (halo rows 0,33 zero); hT aliased (same-wave
// read-before-write) op-chunk stride 72.
__global__ __launch_bounds__(512, 4) void fused_kernel(
    const float* __restrict__ x,
    const float* __restrict__ w1, const float* __restrict__ b1,
    const u16* __restrict__ w2b, const float* __restrict__ b2,
    const u16* __restrict__ whi,
    const float* __restrict__ fcb,
    const float* __restrict__ prew, const float* __restrict__ preb,
    const float* __restrict__ postw, const float* __restrict__ postb,
    const float* __restrict__ Mg,
    float* __restrict__ out)
{
    __shared__ __align__(16) u16 c1h[16 * 1384];     // 44.3 KB
    __shared__ __align__(16) float part2[2 * 1280];  // 10.2 KB fc half partials, stride 20
    __shared__ float prews[256];                     // 1 KB
    __shared__ float Ms[16][17];                     // 1.1 KB
    __shared__ float fcbs[64];                       // 0.25 KB

    const int tid  = threadIdx.x;
    const int bs   = blockIdx.x * 16;
    const int wv   = tid >> 6, lane = tid & 63;
    const int lr   = lane & 15, lq = lane >> 4;

    // ---- stage small tables (ordered before epilogue by barriers A and B) ----
    if (tid < 256) {
        prews[tid] = prew[tid];
        Ms[tid >> 4][tid & 15] = Mg[tid];
    }
    if (tid < 64) fcbs[tid] = fcb[tid];

    // ---- x loads FIRST (vmcnt in-order: conv1's wait won't drain later af loads) ----
    const int s1 = tid >> 5;        // 0..15
    const int pp = tid & 31;        // p = pp+1
    const float* xb = x + (size_t)(bs + s1) * 64;
    const int j = 2 * pp;
    float xm1 = (j == 0)  ? 0.f : xb[j - 1];
    float x0  = xb[j];
    float x1  = xb[j + 1];
    float xp2 = (j == 62) ? 0.f : xb[j + 2];

    // ---- conv2 weight frags issued now; latency hides under conv1 arithmetic ----
    bf16x8 af[3][4];
#pragma unroll
    for (int t = 0; t < 3; ++t)
#pragma unroll
        for (int mt = 0; mt < 4; ++mt)
            af[t][mt] = *(const bf16x8*)(w2b + (size_t)(t * 64 + mt * 16 + lr) * 32 + lq * 8);
    f32x4 bias2[4];
#pragma unroll
    for (int mt = 0; mt < 4; ++mt)
        bias2[mt] = *(const f32x4*)(b2 + mt * 16 + lq * 4);

    // ---- conv1 + relu + pool2 -> c1T; packed-pair math (y0,y1) -> v_pk_fma_f32 ----
    {
        u16* sbase = c1h + s1 * 1384;
        if (pp == 0 || pp == 31) {      // halo rows 0 and 33
            uint4 z = make_uint4(0, 0, 0, 0);
            uint4* zr = (uint4*)(sbase + (pp == 0 ? 0 : 33) * 40);
            zr[0] = z; zr[1] = z; zr[2] = z; zr[3] = z;
        }
        const f32x2 A1 = {xm1, x0};
        const f32x2 A2 = {x0,  x1};
        const f32x2 A3 = {x1,  xp2};
        u32 row[16];
#pragma unroll
        for (int icp = 0; icp < 16; ++icp) {
            float v[2];
#pragma unroll
            for (int h2 = 0; h2 < 2; ++h2) {
                int ic = icp * 2 + h2;
                // wave-uniform indices -> scalar loads on the s-pipe (INVARIANT, R23 lesson)
                float wa = w1[ic * 3], wb = w1[ic * 3 + 1], wc = w1[ic * 3 + 2], bb = b1[ic];
                f32x2 Y = {bb, bb};
                Y += wa * A1;
                Y += wb * A2;
                Y += wc * A3;
                v[h2] = fmaxf(fmaxf(Y.x, Y.y), 0.f);   // pool + relu (v_max3)
            }
            row[icp] = pack_rne(v[0], v[1]);
        }
        uint4* d = (uint4*)(sbase + (1 + pp) * 40);
        d[0] = make_uint4(row[0],  row[1],  row[2],  row[3]);
        d[1] = make_uint4(row[4],  row[5],  row[6],  row[7]);
        d[2] = make_uint4(row[8],  row[9],  row[10], row[11]);
        d[3] = make_uint4(row[12], row[13], row[14], row[15]);
    }
    // NO barrier: conv1 wave wv wrote samples {2wv,2wv+1}; conv2 wave wv reads only those.
    // Same-wave LDS ops are in-order -> RAW safe without __syncthreads.

    // ---- conv2 via MFMA (bias as C-init) + pool -> hT aliased into c1h ----
#pragma unroll
    for (int nt = 0; nt < 4; ++nt) {              // wave wv -> samples 2wv, 2wv+1; two q-halves
        const int s  = wv * 2 + (nt >> 1);
        const int qb = (nt & 1) * 16;
        const u16* bp = c1h + s * 1384 + (qb + lr) * 40 + lq * 8;
        bf16x8 bf0 = *(const bf16x8*)(bp);        // tap t=0
        bf16x8 bf1 = *(const bf16x8*)(bp + 40);   // t=1 (+1 row)
        bf16x8 bf2 = *(const bf16x8*)(bp + 80);   // t=2 (+2 rows)
        const int op = (qb + lr) >> 1;
#pragma unroll
        for (int mt = 0; mt < 4; ++mt) {          // interleaved epilogue: acc live = 4
            f32x4 acc = __builtin_amdgcn_mfma_f32_16x16x32_bf16(af[0][mt], bf0, bias2[mt], 0, 0, 0);
            acc = __builtin_amdgcn_mfma_f32_16x16x32_bf16(af[1][mt], bf1, acc, 0, 0, 0);
            acc = __builtin_amdgcn_mfma_f32_16x16x32_bf16(af[2][mt], bf2, acc, 0, 0, 0);
            float p0 = fmaxf(fmaxf(acc[0], __shfl_xor(acc[0], 1)), 0.f);
            float p1 = fmaxf(fmaxf(acc[1], __shfl_xor(acc[1], 1)), 0.f);
            float p2 = fmaxf(fmaxf(acc[2], __shfl_xor(acc[2], 1)), 0.f);
            float p3 = fmaxf(fmaxf(acc[3], __shfl_xor(acc[3], 1)), 0.f);
            if (!(lane & 1)) {
                *(uint2*)(c1h + s * 1384 + op * 72 + mt * 16 + lq * 4) =
                    make_uint2(pack_rne(p0, p1), pack_rne(p2, p3));
            }
        }
    }
    __syncthreads();   // barrier A: fc reads hT across all samples/waves

    // ---- fc via MFMA on 8 waves: g = wv&3 feature group, hf = wv>>2 kc-half.
    //      Fully unrolled: all 16 whi loads batch -> one L2 latency exposure. ----
    const int g  = wv & 3;
    const int hf = wv >> 2;
    const int n0 = g * 16;
    f32x4 acc0 = {0.f, 0.f, 0.f, 0.f};
    {
        const u16* ab0 = c1h + (size_t)lr * 1384 + lq * 8;
        const u16* bh0 = whi + (size_t)(n0 + lr) * 1024 + hf * 16 * 32 + lq * 8;
#pragma unroll
        for (int i = 0; i < 16; ++i) {
            const int kc = hf * 16 + i;
            const int aoff = (kc >> 1) * 72 + (kc & 1) * 32;
            bf16x8 a0 = *(const bf16x8*)(ab0 + aoff);
            bf16x8 f0 = *(const bf16x8*)(bh0 + i * 32);
            acc0 = __builtin_amdgcn_mfma_f32_16x16x32_bf16(a0, f0, acc0, 0, 0, 0);
        }
    }
    // ALL fc waves store partials: D row = lq*4+r = sample, col = lr -> feature n0+lr
    *(f32x4*)(&part2[hf * 1280 + (n0 + lr) * 20 + lq * 4]) = acc0;
    __syncthreads();   // barrier B (single): partials + tables visible to epilogue

    // ---- epilogue on WAVE 0 at full 64-lane utilization: s = lane>>2, L = lane&3.
    //      h = relu(p0 + p1 + fcb) fused inline from part2 (combine phase deleted). ----
    if (wv == 0) {
        const int L = lane & 3;
        const int s = lane >> 2;

        float a0 = 0.f, a1 = 0.f, a2 = 0.f, a3 = 0.f;
#pragma unroll
        for (int i2 = 0; i2 < 4; ++i2) {
#pragma unroll
            for (int c = 0; c < 4; ++c) {
                int ff = L * 16 + i2 * 4 + c;
                float hx = fmaxf(part2[ff * 20 + s] + part2[1280 + ff * 20 + s] + fcbs[ff], 0.f);
                float4 pw = *(const float4*)&prews[ff * 4];
                a0 = fmaf(hx, pw.x, a0);
                a1 = fmaf(hx, pw.y, a1);
                a2 = fmaf(hx, pw.z, a2);
                a3 = fmaf(hx, pw.w, a3);
            }
        }
        // reduce across the 4 lanes of this sample (xor 1,2 stay within the lane quad)
        a0 += __shfl_xor(a0, 1); a0 += __shfl_xor(a0, 2);
        a1 += __shfl_xor(a1, 1); a1 += __shfl_xor(a1, 2);
        a2 += __shfl_xor(a2, 1); a2 += __shfl_xor(a2, 2);
        a3 += __shfl_xor(a3, 1); a3 += __shfl_xor(a3, 2);

        const float HP = 1.5707963267948966f;
        float qin[4] = { fast_tanh(a0 + preb[0]) * HP, fast_tanh(a1 + preb[1]) * HP,
                         fast_tanh(a2 + preb[2]) * HP, fast_tanh(a3 + preb[3]) * HP };

        float va[4], vb[4];
        const float RS = 0.70710678118654752f;
#pragma unroll
        for (int w = 0; w < 4; ++w) {
            float sw, cw;
            __sincosf(qin[w] * 0.5f, &sw, &cw);
            va[w] = (cw - sw) * RS;
            vb[w] = (sw + cw) * RS;
        }
        float sv[16];
#pragma unroll
        for (int jj = 0; jj < 16; ++jj) {
            float t = (jj & 8) ? vb[0] : va[0];
            t *= (jj & 4) ? vb[1] : va[1];
            t *= (jj & 2) ? vb[2] : va[2];
            t *= (jj & 1) ? vb[3] : va[3];
            sv[jj] = t;
        }
        float z0 = 0.f, z1 = 0.f, z2 = 0.f, z3 = 0.f;
#pragma unroll
        for (int rr = 0; rr < 4; ++rr) {
            const int r = L * 4 + rr;
            float m = 0.f;
#pragma unroll
            for (int jj = 0; jj < 16; ++jj) m = fmaf(Ms[r][jj], sv[jj], m);
            float p = m * m;
            z0 += (r & 8) ? -p : p;
            z1 += (r & 4) ? -p : p;
            z2 += (r & 2) ? -p : p;
            z3 += (r & 1) ? -p : p;
        }
        z0 += __shfl_xor(z0, 1); z0 += __shfl_xor(z0, 2);
        z1 += __shfl_xor(z1, 1); z1 += __shfl_xor(z1, 2);
        z2 += __shfl_xor(z2, 1); z2 += __shfl_xor(z2, 2);
        z3 += __shfl_xor(z3, 1); z3 += __shfl_xor(z3, 2);

        if (L == 0) {
            float t = postb[0] + z0 * postw[0] + z1 * postw[1] + z2 * postw[2] + z3 * postw[3];
            out[bs + s] = 1.f / (1.f + __expf(-t));
        }
    }
}

extern "C" void kernel_launch(void* const* d_in, const int* in_sizes, int n_in,
                              void* d_out, int out_size, void* d_ws, size_t ws_size,
                              hipStream_t stream) {
    const float* x     = (const float*)d_in[0];
    const float* w1    = (const float*)d_in[1];
    const float* b1    = (const float*)d_in[2];
    const float* w2    = (const float*)d_in[3];
    const float* b2    = (const float*)d_in[4];
    const float* fcw   = (const float*)d_in[5];
    const float* fcb   = (const float*)d_in[6];
    const float* prew  = (const float*)d_in[7];
    const float* preb  = (const float*)d_in[8];
    const float* qp    = (const float*)d_in[9];
    const float* postw = (const float*)d_in[10];
    const float* postb = (const float*)d_in[11];
    float* out = (float*)d_out;

    u16*   fwhi = (u16*)d_ws;                           // 64*1024 bf16 = 128 KiB
    float* Mg   = (float*)((char*)d_ws + 131072);       // 1 KiB
    u16*   w2b  = (u16*)((char*)d_ws + 132096);         // 12 KiB

    const int B = in_sizes[0] / 64;   // 32768

    prep_kernel<<<dim3(64), dim3(256), 0, stream>>>(fcw, w2, qp, fwhi, w2b, Mg);
    fused_kernel<<<dim3(B / 16), dim3(512), 0, stream>>>(x, w1, b1, w2b, b2,
                                                         fwhi, fcb, prew, preb,
                                                         postw, postb, Mg, out);
}

// Round 10
// 135.631 us; speedup vs baseline: 1.4090x; 1.0002x over previous
//
#include <hip/hip_runtime.h>
#include <math.h>

typedef unsigned short u16;
typedef unsigned int u32;
typedef __attribute__((ext_vector_type(8))) short bf16x8;   // 8 bf16 = 4 VGPR (MFMA A/B frag)
typedef __attribute__((ext_vector_type(4))) float f32x4;    // MFMA C/D frag
typedef __attribute__((ext_vector_type(2))) float f32x2;    // packed fp32 pair (v_pk_fma_f32)

__device__ __forceinline__ u16 f32_to_bf16(float f) {
    u32 u = __float_as_uint(f);
    u32 r = u + 0x7FFFu + ((u >> 16) & 1u);   // round-to-nearest-even
    return (u16)(r >> 16);
}
__device__ __forceinline__ u32 pack2(u16 a, u16 b) { return (u32)a | ((u32)b << 16); }

// HW packed f32->bf16 RNE: lo = bf16(a), hi = bf16(b). 1 inst vs 9 for manual RNE+perm.
// (no builtin on gfx950 -> inline asm; same rounding as the manual path, m214v22 idiom)
__device__ __forceinline__ u32 cvt_pk_bf16(float a, float b) {
    u32 r;
    asm("v_cvt_pk_bf16_f32 %0, %1, %2" : "=v"(r) : "v"(a), "v"(b));
    return r;
}

// fast tanh via hardware exp
__device__ __forceinline__ float fast_tanh(float x) {
    float e = __expf(2.f * x);
    return 1.f - 2.f / (e + 1.f);
}

// ---------------- quantum gate helpers (prep only; precise libm) ----------------
template<int STRIDE>
__device__ __forceinline__ void ry_gate(float st[16], float theta) {
    float s, c;
    sincosf(theta * 0.5f, &s, &c);
#pragma unroll
    for (int i = 0; i < 16; ++i) {
        if (i & STRIDE) continue;
        float s0 = st[i], s1 = st[i | STRIDE];
        st[i]          = c * s0 - s * s1;
        st[i | STRIDE] = fmaf(s, s0, c * s1);
    }
}
template<int CS, int TS>
__device__ __forceinline__ void cnot_gate(float st[16]) {
#pragma unroll
    for (int i = 0; i < 16; ++i) {
        if ((i & CS) && !(i & TS)) {
            float tmp = st[i]; st[i] = st[i | TS]; st[i | TS] = tmp;
        }
    }
}

// ---------------- Prep: fcw transpose->bf16, w2->bf16 frag layout, circuit matrix M ----------
// whi: [f][k = op*64+oc] (k_ref = oc*16+op). w2b: [(t*64+oc)*32+ic] bf16.
__global__ __launch_bounds__(256) void prep_kernel(
    const float* __restrict__ fcw, const float* __restrict__ w2,
    const float* __restrict__ qp,
    u16* __restrict__ whi, u16* __restrict__ w2b, float* __restrict__ Mg)
{
    const int f  = blockIdx.x;         // 0..63
    const int k0 = threadIdx.x * 4;    // 0..1020
    u16 hv[4];
#pragma unroll
    for (int i = 0; i < 4; ++i) {
        int k  = k0 + i;
        int op = k >> 6, oc = k & 63;
        hv[i] = f32_to_bf16(fcw[(size_t)(oc * 16 + op) * 64 + f]);
    }
    *(uint2*)(whi + (size_t)f * 1024 + k0) = make_uint2(pack2(hv[0], hv[1]), pack2(hv[2], hv[3]));

    if (threadIdx.x < 96) {
        const int j  = threadIdx.x;
        const int ic = j / 3, t = j - ic * 3;
        w2b[(t * 64 + f) * 32 + ic] = f32_to_bf16(w2[f * 96 + j]);
    }

    if (blockIdx.x == 0 && threadIdx.x < 16) {
        const int j = threadIdx.x;
        float st[16];
#pragma unroll
        for (int i = 0; i < 16; ++i) st[i] = (i == j) ? 1.f : 0.f;
        for (int k = 0; k < 6; ++k) {
            cnot_gate<8, 4>(st);   // CNOT(0,1)
            cnot_gate<2, 1>(st);   // CNOT(2,3)
            cnot_gate<4, 2>(st);   // CNOT(1,2)
            ry_gate<8>(st, qp[k * 4 + 0]);
            ry_gate<4>(st, qp[k * 4 + 1]);
            ry_gate<2>(st, qp[k * 4 + 2]);
            ry_gate<1>(st, qp[k * 4 + 3]);
        }
#pragma unroll
        for (int i = 0; i < 16; ++i) Mg[i * 16 + j] = st[i];
    }
}

// ---------------- Fused: conv1 -> conv2(MFMA) -> fc(MFMA) -> quantum epilogue ----------------
// R25 = R24 (58.9us champion) + 4 local latency/VALU cuts, no layout/sync changes.
// R24 post-mortem: barrier merge WIN (62->58.9); VALU issue arithmetic now fully explains
// VALUBusy 29% (64 waves/CU x ~350 insts x 2cyc ~= 45k cyc) -> remaining levers are VALU
// inst count + dep-chain length, not structure.
//  (1) conv1 x-load: float2 + shfl_up/down (4 scalar VMEM -> 1 coalesced 8B; pp==0/31
//      boundary lanes already mask xm1/xp2 to the zero-pad value).
//  (2) v_cvt_pk_bf16_f32 replaces manual RNE pack (9 VALU -> 1) in conv1 rows + conv2 hT
//      writes (same RNE rounding; passes identical absmax).
//  (3) fc dual accumulator: 16-deep MFMA chain -> 2x8 + vector add (f32 reorder only).
//  (4) epilogue part2 reads visited as cc=(c+L)&3: staggers banks by 20L mod 32 ->
//      4-way conflict -> conflict-free (accumulation order irrelevant).
// Carried invariants: conv1 weight indices wave-uniform (R23 lesson: lane-varying w1/b1
// kills the s-pipe broadcast); no barrier before conv2 (conv1 wave wv writes exactly
// samples {2wv,2wv+1}, conv2 wave wv reads only those - same-wave in-order LDS); conv2
// weight frags issued after x loads, before conv1 arithmetic (vmcnt in-order); single
// barrier B with all-8-wave partial store to part2[2][1280] stride 20; epilogue wave 0
// full 64-lane (s=lane>>2, L=lane&3 - R19-verified). (512,4) = VGPR cap 128. Per-sample
// c1h block (1384 u16): c1T rows p[0,34) stride 40 (halo rows 0,33 zero); hT aliased
// op-chunk stride 72. Spill canary: WRITE_SIZE ~0.13MB.
__global__ __launch_bounds__(512, 4) void fused_kernel(
    const float* __restrict__ x,
    const float* __restrict__ w1, const float* __restrict__ b1,
    const u16* __restrict__ w2b, const float* __restrict__ b2,
    const u16* __restrict__ whi,
    const float* __restrict__ fcb,
    const float* __restrict__ prew, const float* __restrict__ preb,
    const float* __restrict__ postw, const float* __restrict__ postb,
    const float* __restrict__ Mg,
    float* __restrict__ out)
{
    __shared__ __align__(16) u16 c1h[16 * 1384];     // 44.3 KB
    __shared__ __align__(16) float part2[2 * 1280];  // 10.2 KB fc half partials, stride 20
    __shared__ float prews[256];                     // 1 KB
    __shared__ float Ms[16][17];                     // 1.1 KB
    __shared__ float fcbs[64];                       // 0.25 KB

    const int tid  = threadIdx.x;
    const int bs   = blockIdx.x * 16;
    const int wv   = tid >> 6, lane = tid & 63;
    const int lr   = lane & 15, lq = lane >> 4;

    // ---- stage small tables (ordered before epilogue by barriers A and B) ----
    if (tid < 256) {
        prews[tid] = prew[tid];
        Ms[tid >> 4][tid & 15] = Mg[tid];
    }
    if (tid < 64) fcbs[tid] = fcb[tid];

    // ---- x loads FIRST (vmcnt in-order: conv1's wait won't drain later af loads) ----
    const int s1 = tid >> 5;        // 0..15
    const int pp = tid & 31;        // p = pp+1
    const float* xb = x + (size_t)(bs + s1) * 64;
    const int j = 2 * pp;
    const float2 xv = *(const float2*)(xb + j);   // one coalesced 8B load
    float x0 = xv.x, x1 = xv.y;

    // ---- conv2 weight frags issued now; latency hides under conv1 arithmetic ----
    bf16x8 af[3][4];
#pragma unroll
    for (int t = 0; t < 3; ++t)
#pragma unroll
        for (int mt = 0; mt < 4; ++mt)
            af[t][mt] = *(const bf16x8*)(w2b + (size_t)(t * 64 + mt * 16 + lr) * 32 + lq * 8);
    f32x4 bias2[4];
#pragma unroll
    for (int mt = 0; mt < 4; ++mt)
        bias2[mt] = *(const f32x4*)(b2 + mt * 16 + lq * 4);

    // neighbors via cross-lane (sample boundaries masked to the zero pad):
    float xm1 = __shfl_up(x1, 1);   if (pp == 0)  xm1 = 0.f;
    float xp2 = __shfl_down(x0, 1); if (pp == 31) xp2 = 0.f;

    // ---- conv1 + relu + pool2 -> c1T; packed-pair math (y0,y1) -> v_pk_fma_f32 ----
    {
        u16* sbase = c1h + s1 * 1384;
        if (pp == 0 || pp == 31) {      // halo rows 0 and 33
            uint4 z = make_uint4(0, 0, 0, 0);
            uint4* zr = (uint4*)(sbase + (pp == 0 ? 0 : 33) * 40);
            zr[0] = z; zr[1] = z; zr[2] = z; zr[3] = z;
        }
        const f32x2 A1 = {xm1, x0};
        const f32x2 A2 = {x0,  x1};
        const f32x2 A3 = {x1,  xp2};
        u32 row[16];
#pragma unroll
        for (int icp = 0; icp < 16; ++icp) {
            float v[2];
#pragma unroll
            for (int h2 = 0; h2 < 2; ++h2) {
                int ic = icp * 2 + h2;
                // wave-uniform indices -> scalar loads on the s-pipe (INVARIANT, R23 lesson)
                float wa = w1[ic * 3], wb = w1[ic * 3 + 1], wc = w1[ic * 3 + 2], bb = b1[ic];
                f32x2 Y = {bb, bb};
                Y += wa * A1;
                Y += wb * A2;
                Y += wc * A3;
                v[h2] = fmaxf(fmaxf(Y.x, Y.y), 0.f);   // pool + relu (v_max3)
            }
            row[icp] = cvt_pk_bf16(v[0], v[1]);
        }
        uint4* d = (uint4*)(sbase + (1 + pp) * 40);
        d[0] = make_uint4(row[0],  row[1],  row[2],  row[3]);
        d[1] = make_uint4(row[4],  row[5],  row[6],  row[7]);
        d[2] = make_uint4(row[8],  row[9],  row[10], row[11]);
        d[3] = make_uint4(row[12], row[13], row[14], row[15]);
    }
    // NO barrier: conv1 wave wv wrote samples {2wv,2wv+1}; conv2 wave wv reads only those.
    // Same-wave LDS ops are in-order -> RAW safe without __syncthreads.

    // ---- conv2 via MFMA (bias as C-init) + pool -> hT aliased into c1h ----
#pragma unroll
    for (int nt = 0; nt < 4; ++nt) {              // wave wv -> samples 2wv, 2wv+1; two q-halves
        const int s  = wv * 2 + (nt >> 1);
        const int qb = (nt & 1) * 16;
        const u16* bp = c1h + s * 1384 + (qb + lr) * 40 + lq * 8;
        bf16x8 bf0 = *(const bf16x8*)(bp);        // tap t=0
        bf16x8 bf1 = *(const bf16x8*)(bp + 40);   // t=1 (+1 row)
        bf16x8 bf2 = *(const bf16x8*)(bp + 80);   // t=2 (+2 rows)
        const int op = (qb + lr) >> 1;
#pragma unroll
        for (int mt = 0; mt < 4; ++mt) {          // interleaved epilogue: acc live = 4
            f32x4 acc = __builtin_amdgcn_mfma_f32_16x16x32_bf16(af[0][mt], bf0, bias2[mt], 0, 0, 0);
            acc = __builtin_amdgcn_mfma_f32_16x16x32_bf16(af[1][mt], bf1, acc, 0, 0, 0);
            acc = __builtin_amdgcn_mfma_f32_16x16x32_bf16(af[2][mt], bf2, acc, 0, 0, 0);
            float p0 = fmaxf(fmaxf(acc[0], __shfl_xor(acc[0], 1)), 0.f);
            float p1 = fmaxf(fmaxf(acc[1], __shfl_xor(acc[1], 1)), 0.f);
            float p2 = fmaxf(fmaxf(acc[2], __shfl_xor(acc[2], 1)), 0.f);
            float p3 = fmaxf(fmaxf(acc[3], __shfl_xor(acc[3], 1)), 0.f);
            if (!(lane & 1)) {
                *(uint2*)(c1h + s * 1384 + op * 72 + mt * 16 + lq * 4) =
                    make_uint2(cvt_pk_bf16(p0, p1), cvt_pk_bf16(p2, p3));
            }
        }
    }
    __syncthreads();   // barrier A: fc reads hT across all samples/waves

    // ---- fc via MFMA on 8 waves: g = wv&3 feature group, hf = wv>>2 kc-half.
    //      Fully unrolled, DUAL accumulator (2x8 chain instead of 16-deep). ----
    const int g  = wv & 3;
    const int hf = wv >> 2;
    const int n0 = g * 16;
    f32x4 accA = {0.f, 0.f, 0.f, 0.f};
    f32x4 accB = {0.f, 0.f, 0.f, 0.f};
    {
        const u16* ab0 = c1h + (size_t)lr * 1384 + lq * 8;
        const u16* bh0 = whi + (size_t)(n0 + lr) * 1024 + hf * 16 * 32 + lq * 8;
#pragma unroll
        for (int i = 0; i < 16; i += 2) {
            const int kcA = hf * 16 + i;
            const int kcB = kcA + 1;
            const int aoffA = (kcA >> 1) * 72 + (kcA & 1) * 32;
            const int aoffB = (kcB >> 1) * 72 + (kcB & 1) * 32;
            bf16x8 a0 = *(const bf16x8*)(ab0 + aoffA);
            bf16x8 a1 = *(const bf16x8*)(ab0 + aoffB);
            bf16x8 f0 = *(const bf16x8*)(bh0 + i * 32);
            bf16x8 f1 = *(const bf16x8*)(bh0 + (i + 1) * 32);
            accA = __builtin_amdgcn_mfma_f32_16x16x32_bf16(a0, f0, accA, 0, 0, 0);
            accB = __builtin_amdgcn_mfma_f32_16x16x32_bf16(a1, f1, accB, 0, 0, 0);
        }
    }
    const f32x4 acc0 = accA + accB;
    // ALL fc waves store partials: D row = lq*4+r = sample, col = lr -> feature n0+lr
    *(f32x4*)(&part2[hf * 1280 + (n0 + lr) * 20 + lq * 4]) = acc0;
    __syncthreads();   // barrier B (single): partials + tables visible to epilogue

    // ---- epilogue on WAVE 0 at full 64-lane utilization: s = lane>>2, L = lane&3.
    //      h = relu(p0 + p1 + fcb) fused inline from part2; cc=(c+L)&3 visit order
    //      staggers part2 banks by 20L -> conflict-free. ----
    if (wv == 0) {
        const int L = lane & 3;
        const int s = lane >> 2;

        float a0 = 0.f, a1 = 0.f, a2 = 0.f, a3 = 0.f;
#pragma unroll
        for (int i2 = 0; i2 < 4; ++i2) {
#pragma unroll
            for (int c = 0; c < 4; ++c) {
                int cc = (c + L) & 3;
                int ff = L * 16 + i2 * 4 + cc;
                float hx = fmaxf(part2[ff * 20 + s] + part2[1280 + ff * 20 + s] + fcbs[ff], 0.f);
                float4 pw = *(const float4*)&prews[ff * 4];
                a0 = fmaf(hx, pw.x, a0);
                a1 = fmaf(hx, pw.y, a1);
                a2 = fmaf(hx, pw.z, a2);
                a3 = fmaf(hx, pw.w, a3);
            }
        }
        // reduce across the 4 lanes of this sample (xor 1,2 stay within the lane quad)
        a0 += __shfl_xor(a0, 1); a0 += __shfl_xor(a0, 2);
        a1 += __shfl_xor(a1, 1); a1 += __shfl_xor(a1, 2);
        a2 += __shfl_xor(a2, 1); a2 += __shfl_xor(a2, 2);
        a3 += __shfl_xor(a3, 1); a3 += __shfl_xor(a3, 2);

        const float HP = 1.5707963267948966f;
        float qin[4] = { fast_tanh(a0 + preb[0]) * HP, fast_tanh(a1 + preb[1]) * HP,
                         fast_tanh(a2 + preb[2]) * HP, fast_tanh(a3 + preb[3]) * HP };

        float va[4], vb[4];
        const float RS = 0.70710678118654752f;
#pragma unroll
        for (int w = 0; w < 4; ++w) {
            float sw, cw;
            __sincosf(qin[w] * 0.5f, &sw, &cw);
            va[w] = (cw - sw) * RS;
            vb[w] = (sw + cw) * RS;
        }
        float sv[16];
#pragma unroll
        for (int jj = 0; jj < 16; ++jj) {
            float t = (jj & 8) ? vb[0] : va[0];
            t *= (jj & 4) ? vb[1] : va[1];
            t *= (jj & 2) ? vb[2] : va[2];
            t *= (jj & 1) ? vb[3] : va[3];
            sv[jj] = t;
        }
        float z0 = 0.f, z1 = 0.f, z2 = 0.f, z3 = 0.f;
#pragma unroll
        for (int rr = 0; rr < 4; ++rr) {
            const int r = L * 4 + rr;
            float m = 0.f;
#pragma unroll
            for (int jj = 0; jj < 16; ++jj) m = fmaf(Ms[r][jj], sv[jj], m);
            float p = m * m;
            z0 += (r & 8) ? -p : p;
            z1 += (r & 4) ? -p : p;
            z2 += (r & 2) ? -p : p;
            z3 += (r & 1) ? -p : p;
        }
        z0 += __shfl_xor(z0, 1); z0 += __shfl_xor(z0, 2);
        z1 += __shfl_xor(z1, 1); z1 += __shfl_xor(z1, 2);
        z2 += __shfl_xor(z2, 1); z2 += __shfl_xor(z2, 2);
        z3 += __shfl_xor(z3, 1); z3 += __shfl_xor(z3, 2);

        if (L == 0) {
            float t = postb[0] + z0 * postw[0] + z1 * postw[1] + z2 * postw[2] + z3 * postw[3];
            out[bs + s] = 1.f / (1.f + __expf(-t));
        }
    }
}

extern "C" void kernel_launch(void* const* d_in, const int* in_sizes, int n_in,
                              void* d_out, int out_size, void* d_ws, size_t ws_size,
                              hipStream_t stream) {
    const float* x     = (const float*)d_in[0];
    const float* w1    = (const float*)d_in[1];
    const float* b1    = (const float*)d_in[2];
    const float* w2    = (const float*)d_in[3];
    const float* b2    = (const float*)d_in[4];
    const float* fcw   = (const float*)d_in[5];
    const float* fcb   = (const float*)d_in[6];
    const float* prew  = (const float*)d_in[7];
    const float* preb  = (const float*)d_in[8];
    const float* qp    = (const float*)d_in[9];
    const float* postw = (const float*)d_in[10];
    const float* postb = (const float*)d_in[11];
    float* out = (float*)d_out;

    u16*   fwhi = (u16*)d_ws;                           // 64*1024 bf16 = 128 KiB
    float* Mg   = (float*)((char*)d_ws + 131072);       // 1 KiB
    u16*   w2b  = (u16*)((char*)d_ws + 132096);         // 12 KiB

    const int B = in_sizes[0] / 64;   // 32768

    prep_kernel<<<dim3(64), dim3(256), 0, stream>>>(fcw, w2, qp, fwhi, w2b, Mg);
    fused_kernel<<<dim3(B / 16), dim3(512), 0, stream>>>(x, w1, b1, w2b, b2,
                                                         fwhi, fcb, prew, preb,
                                                         postw, postb, Mg, out);
}